// Round 7
// baseline (113.562 us; speedup 1.0000x reference)
//
#include <hip/hip_runtime.h>
#include <hip/hip_bf16.h>
#include <stdint.h>

#define B_  4
#define L_  1024
#define C_  512
#define D_  64
#define BH_ 32
#define M_  4096

typedef short  bf16x8 __attribute__((ext_vector_type(8)));
typedef float  f32x4  __attribute__((ext_vector_type(4)));
typedef unsigned short u16x8 __attribute__((ext_vector_type(8)));
typedef unsigned int   u32x2 __attribute__((ext_vector_type(2)));

__device__ __forceinline__ unsigned short f2bf(float f) {
    union { float f; uint32_t u; } v; v.f = f;
    uint32_t u = v.u;
    return (unsigned short)((u + 0x7fffu + ((u >> 16) & 1u)) >> 16);
}
__device__ __forceinline__ float bf2f(unsigned short s) {
    union { uint32_t u; float f; } v; v.u = ((uint32_t)s) << 16;
    return v.f;
}

// async global->LDS, 16B per lane; LDS dest = wave-uniform base + lane*16
__device__ __forceinline__ void gload16(const void* g, void* s) {
    __builtin_amdgcn_global_load_lds((const __attribute__((address_space(1))) void*)g,
                                     (__attribute__((address_space(3))) void*)s, 16, 0, 0);
}

// ---------------- f32 -> bf16 convert (weights only; x fused into qkv GEMM) ----------------
#define NWQ4  (3 * C_ * C_ / 4)        // 196608
#define NWP4  (C_ * C_ / 4)            // 65536
__global__ void cvt_w(const float* __restrict__ wq, const float* __restrict__ wp,
                      unsigned short* __restrict__ wqb, unsigned short* __restrict__ wpb) {
    int i = blockIdx.x * 256 + threadIdx.x;
    const float* src; unsigned short* dst; int o;
    if (i < NWQ4) { src = wq; dst = wqb; o = i; }
    else if (i < NWQ4 + NWP4) { src = wp; dst = wpb; o = i - NWQ4; }
    else return;
    float4 v = ((const float4*)src)[o];
    ushort4 r;
    r.x = f2bf(v.x); r.y = f2bf(v.y); r.z = f2bf(v.z); r.w = f2bf(v.w);
    ((ushort4*)dst)[o] = r;
}

// ---------------- precompute E = exp(bias), symmetric-pair blocks ----------------
// EI layout: [b][q16(64)][k16(64)][lane(64)][ef x4 | eb x4] bf16 (16B per lane).
// lane l=(c,g), elem e: q = q16*16 + c, k = k16*16 + 4g + e.
// Block (i,j), i<=j stages adj tiles (i,j) and (j,i) once, emits EI(i,j) and EI(j,i).
__global__ __launch_bounds__(256) void prep_e(const float* __restrict__ adj,
                                              const float* __restrict__ bias_scale,
                                              unsigned short* __restrict__ EI) {
    const int bI = blockIdx.z;
    const int i = blockIdx.y, j = blockIdx.x;
    if (j < i) return;
    __shared__ float Ta[64][68];   // adj[i-rows][j-cols]
    __shared__ float Tb[64][68];   // adj[j-rows][i-cols]
    const float* adjb = adj + (size_t)bI * L_ * L_;
    const int tid = threadIdx.x;
#pragma unroll
    for (int s = 0; s < 4; ++s) {
        int idx = s * 256 + tid;                 // 0..1023
        int r = idx >> 4, c4 = (idx & 15) * 4;
        float4 va = *(const float4*)(adjb + (size_t)(i * 64 + r) * L_ + j * 64 + c4);
        float4 vb = *(const float4*)(adjb + (size_t)(j * 64 + r) * L_ + i * 64 + c4);
        *(float4*)&Ta[r][c4] = va;
        *(float4*)&Tb[r][c4] = vb;
    }
    __syncthreads();
    const float bs0 = bias_scale[0], bs1 = bias_scale[1];
    const int w = tid >> 6, l = tid & 63, g = l >> 4, c = l & 15;
    const int kloc = w * 16 + g * 4;
#pragma unroll
    for (int qs = 0; qs < 4; ++qs) {
        const int qloc = qs * 16 + c;
        {   // output tile (qb=i, kb=j): ef from Ta direct, eb from Tb transposed
            int qg = i * 64 + qloc, kgb = j * 64 + kloc;
            unsigned short ef[4], eb[4];
#pragma unroll
            for (int e = 0; e < 4; ++e) {
                bool z = (qg == 0) || (kgb + e == 0);
                ef[e] = f2bf(z ? 1.0f : __expf(bs0 * Ta[qloc][kloc + e]));
                eb[e] = f2bf(z ? 1.0f : __expf(bs1 * Tb[kloc + e][qloc]));
            }
            size_t o = (((size_t)bI * 64 + (i * 4 + qs)) * 64 + (j * 4 + w)) * 512 + (size_t)l * 8;
            *(u16x8*)(EI + o) = (u16x8){ef[0], ef[1], ef[2], ef[3], eb[0], eb[1], eb[2], eb[3]};
        }
        if (i != j) {  // mirrored tile (qb=j, kb=i): ef from Tb direct, eb from Ta transposed
            int qg = j * 64 + qloc, kgb = i * 64 + kloc;
            unsigned short ef[4], eb[4];
#pragma unroll
            for (int e = 0; e < 4; ++e) {
                bool z = (qg == 0) || (kgb + e == 0);
                ef[e] = f2bf(z ? 1.0f : __expf(bs0 * Tb[qloc][kloc + e]));
                eb[e] = f2bf(z ? 1.0f : __expf(bs1 * Ta[kloc + e][qloc]));
            }
            size_t o = (((size_t)bI * 64 + (j * 4 + qs)) * 64 + (i * 4 + w)) * 512 + (size_t)l * 8;
            *(u16x8*)(EI + o) = (u16x8){ef[0], ef[1], ef[2], ef[3], eb[0], eb[1], eb[2], eb[3]};
        }
    }
}

// ---------------- bf16 MFMA GEMM: out[M,N] = A[M,K] * B[N,K]^T ----------------
// AF32: A read as f32 and converted during staging. EPI 0: scatter qkv. EPI 1: f32 store.
template <int BM, int BN, int KDIM, int EPI, int NDIM, bool AF32>
__global__ __launch_bounds__(256, 4) void gemm_bf16(const unsigned short* __restrict__ Amat,
                                                    const float* __restrict__ Af,
                                                    const unsigned short* __restrict__ Bmat,
                                                    float* __restrict__ outp,
                                                    unsigned short* __restrict__ q_out,
                                                    unsigned short* __restrict__ k_out,
                                                    unsigned short* __restrict__ v_out) {
    constexpr int NA = BM / 32, NB = BN / 32;
    constexpr int MI = BM / 32, NI = BN / 32;
    __shared__ __align__(16) unsigned short As[BM * 64];
    __shared__ __align__(16) unsigned short Bs[BN * 64];
    const int tid = threadIdx.x;
    const int l = tid & 63, wid = tid >> 6;
    const int g = l >> 4, c = l & 15;
    const int wr = wid >> 1, wc = wid & 1;
    const int row0 = blockIdx.y * BM, col0 = blockIdx.x * BN;

    f32x4 acc[MI][NI];
#pragma unroll
    for (int mi = 0; mi < MI; ++mi)
#pragma unroll
        for (int ni = 0; ni < NI; ++ni) acc[mi][ni] = (f32x4){0.f, 0.f, 0.f, 0.f};

    for (int k0 = 0; k0 < KDIM; k0 += 64) {
        bf16x8 ra[NA], rb[NB];
#pragma unroll
        for (int i = 0; i < NA; ++i) {
            int q = i * 256 + tid;
            int r = q >> 3;
            if constexpr (AF32) {
                const float* ap = Af + (size_t)(row0 + r) * KDIM + k0 + (q & 7) * 8;
                float4 v0 = *(const float4*)ap;
                float4 v1 = *(const float4*)(ap + 4);
                union { unsigned short s[8]; bf16x8 v; } u;
                u.s[0] = f2bf(v0.x); u.s[1] = f2bf(v0.y); u.s[2] = f2bf(v0.z); u.s[3] = f2bf(v0.w);
                u.s[4] = f2bf(v1.x); u.s[5] = f2bf(v1.y); u.s[6] = f2bf(v1.z); u.s[7] = f2bf(v1.w);
                ra[i] = u.v;
            } else {
                ra[i] = *(const bf16x8*)((const char*)Amat + (size_t)(row0 + r) * (KDIM * 2) + k0 * 2 + (q & 7) * 16);
            }
        }
#pragma unroll
        for (int i = 0; i < NB; ++i) {
            int q = i * 256 + tid;
            int r = q >> 3, cb = (q & 7) * 16;
            rb[i] = *(const bf16x8*)((const char*)Bmat + (size_t)(col0 + r) * (KDIM * 2) + k0 * 2 + cb);
        }
        __syncthreads();
#pragma unroll
        for (int i = 0; i < NA; ++i) {
            int q = i * 256 + tid;
            int r = q >> 3, cb = (q & 7) * 16;
            *(bf16x8*)((char*)As + r * 128 + (cb ^ ((r & 7) << 4))) = ra[i];
        }
#pragma unroll
        for (int i = 0; i < NB; ++i) {
            int q = i * 256 + tid;
            int r = q >> 3, cb = (q & 7) * 16;
            *(bf16x8*)((char*)Bs + r * 128 + (cb ^ ((r & 7) << 4))) = rb[i];
        }
        __syncthreads();
#pragma unroll
        for (int kk = 0; kk < 2; ++kk) {
            bf16x8 afr[MI], bfr[NI];
#pragma unroll
            for (int mi = 0; mi < MI; ++mi) {
                int r = wr * (BM / 2) + mi * 16 + c;
                afr[mi] = *(const bf16x8*)((const char*)As + r * 128 + ((kk * 64 + g * 16) ^ ((r & 7) << 4)));
            }
#pragma unroll
            for (int ni = 0; ni < NI; ++ni) {
                int r = wc * (BN / 2) + ni * 16 + c;
                bfr[ni] = *(const bf16x8*)((const char*)Bs + r * 128 + ((kk * 64 + g * 16) ^ ((r & 7) << 4)));
            }
#pragma unroll
            for (int mi = 0; mi < MI; ++mi)
#pragma unroll
                for (int ni = 0; ni < NI; ++ni)
                    acc[mi][ni] = __builtin_amdgcn_mfma_f32_16x16x32_bf16(afr[mi], bfr[ni], acc[mi][ni], 0, 0, 0);
        }
    }
#pragma unroll
    for (int mi = 0; mi < MI; ++mi) {
#pragma unroll
        for (int ni = 0; ni < NI; ++ni) {
#pragma unroll
            for (int ii = 0; ii < 4; ++ii) {
                int m = row0 + wr * (BM / 2) + mi * 16 + g * 4 + ii;
                int n = col0 + wc * (BN / 2) + ni * 16 + c;
                float val = acc[mi][ni][ii];
                if (EPI == 0) {
                    unsigned short v = f2bf(val);
                    int b = m >> 10, ll = m & 1023;
                    int which = n >> 9, cc = n & 511;
                    int hh = cc >> 6, d = cc & 63;
                    int bh = b * 8 + hh;
                    if (which == 0)      q_out[((size_t)bh * L_ + ll) * D_ + d] = v;
                    else if (which == 1) k_out[((size_t)bh * L_ + ll) * D_ + d] = v;
                    else                 v_out[((size_t)bh * D_ + d) * L_ + ll] = v;
                } else {
                    outp[(size_t)m * NDIM + n] = val;
                }
            }
        }
    }
}

// ---------------- fused 3-branch attention: depth-2 counted-vmcnt pipeline ----------------
// 4 rotating LDS buffers (16KB each: K 8KB | V 8KB); stage tile t+2 while computing t.
// Per phase: 4 gload_lds + 4 E-loads = 8 vmem ops; at tile-t's wait the ops younger than
// stage(t) are E(t)+S(t+1)+E(t+1) = 12 -> s_waitcnt vmcnt(12) (final phase: 4).
struct EReg { bf16x8 e[4]; };

__global__ __launch_bounds__(256, 2) void attn_kernel(const unsigned short* __restrict__ Qb,
                                                      const unsigned short* __restrict__ Kb,
                                                      const unsigned short* __restrict__ Vtb,
                                                      const unsigned short* __restrict__ EI,
                                                      const float* __restrict__ beta,
                                                      unsigned short* __restrict__ hb) {
    __shared__ __align__(16) char smem[4][16384];
    const int tid = threadIdx.x;
    const int w = tid >> 6, l = tid & 63;
    const int g = l >> 4, c = l & 15;

    // XCD-grouping swizzle: 8 head-blocks sharing one (b,q64) EI slice -> same XCD.
    const int p = blockIdx.x;                 // 0..511
    const int s = (p & 7) + 8 * (p >> 6);     // (b, qb) index 0..63
    const int h = (p >> 3) & 7;
    const int b = s >> 4, qb = s & 15;
    const int bh = b * 8 + h;
    const int q0 = qb * 64 + w * 16;
    const int qt = qb * 4 + w;

    const unsigned short* Qrow = Qb + ((size_t)bh * L_ + q0 + c) * D_;
    const bf16x8 qf0 = *(const bf16x8*)(Qrow + g * 8);
    const bf16x8 qf1 = *(const bf16x8*)(Qrow + 32 + g * 8);
    asm volatile("s_waitcnt vmcnt(0)" ::: "memory");   // clean vmcnt before counted pipeline

    const unsigned short* Kbase = Kb + (size_t)bh * L_ * D_;   // row stride 64
    const unsigned short* Vbase = Vtb + (size_t)bh * D_ * L_;  // row stride 1024
    const unsigned short* Ebase = EI + ((size_t)(b * 64 + qt) * 64) * 512;

    f32x4 O[3][4];
#pragma unroll
    for (int j = 0; j < 3; ++j)
#pragma unroll
        for (int dc = 0; dc < 4; ++dc) O[j][dc] = (f32x4){0.f, 0.f, 0.f, 0.f};
    float lsum0 = 0.f, lsum1 = 0.f, lsum2 = 0.f;

    const int srow = l >> 3, sm = l & 7;       // staging row-within-8, chunk
    const int key = (c & 7) << 4;              // read-side swizzle key

    auto stage = [&](int t, char* base) {      // 4 vmem ops per wave
#pragma unroll
        for (int n = 0; n < 2; ++n) {
            int i = 2 * w + n;
            int row = i * 8 + srow;
            int sw = (sm ^ (row & 7)) * 8;     // pre-swizzled global source
            gload16(Kbase + (size_t)(t * 64 + row) * D_ + sw, base + i * 1024);
            gload16(Vbase + (size_t)row * L_ + t * 64 + sw, base + 8192 + i * 1024);
        }
    };
    auto eload = [&](EReg& X, int t) {         // 4 vmem ops per wave
#pragma unroll
        for (int ks = 0; ks < 4; ++ks)
            X.e[ks] = *(const bf16x8*)(Ebase + (size_t)(t * 4 + ks) * 512 + l * 8);
    };

    auto computeS = [&](const char* base, const EReg& E, unsigned (&rr)[4][3][2]) {
        const char* Kl = base;
#pragma unroll
        for (int st = 0; st < 4; ++st) {
            const char* kr = Kl + (st * 16 + c) * 128;
            bf16x8 ka = *(const bf16x8*)(kr + ((g * 16) ^ key));
            bf16x8 kb = *(const bf16x8*)(kr + ((64 + g * 16) ^ key));
            f32x4 sacc = (f32x4){0.f, 0.f, 0.f, 0.f};
            sacc = __builtin_amdgcn_mfma_f32_16x16x32_bf16(ka, qf0, sacc, 0, 0, 0);
            sacc = __builtin_amdgcn_mfma_f32_16x16x32_bf16(kb, qf1, sacc, 0, 0, 0);
            float pv[3][4];
#pragma unroll
            for (int i = 0; i < 4; ++i) {
                float p0 = __expf(sacc[i] * 0.125f);
                float p1 = p0 * bf2f((unsigned short)E.e[st][i]);
                float p2 = p0 * bf2f((unsigned short)E.e[st][4 + i]);
                lsum0 += p0; lsum1 += p1; lsum2 += p2;
                pv[0][i] = p0; pv[1][i] = p1; pv[2][i] = p2;
            }
#pragma unroll
            for (int j = 0; j < 3; ++j) {
                rr[st][j][0] = __builtin_amdgcn_perm(__float_as_uint(pv[j][1]), __float_as_uint(pv[j][0]), 0x07060302u);
                rr[st][j][1] = __builtin_amdgcn_perm(__float_as_uint(pv[j][3]), __float_as_uint(pv[j][2]), 0x07060302u);
            }
        }
    };

    auto computePV = [&](const char* base, const unsigned (&rr)[4][3][2]) {
        const char* Vl = base + 8192;
#pragma unroll
        for (int kk = 0; kk < 2; ++kk) {
            bf16x8 af[3];
#pragma unroll
            for (int j = 0; j < 3; ++j) {
                union { unsigned u[4]; bf16x8 v; } t_;
                t_.u[0] = rr[2 * kk][j][0];     t_.u[1] = rr[2 * kk][j][1];
                t_.u[2] = rr[2 * kk + 1][j][0]; t_.u[3] = rr[2 * kk + 1][j][1];
                af[j] = t_.v;
            }
#pragma unroll
            for (int dc = 0; dc < 4; ++dc) {
                const char* vr = Vl + (dc * 16 + c) * 128;
                u32x2 vlo = *(const u32x2*)(vr + ((kk * 64 + g * 8) ^ key));
                u32x2 vhi = *(const u32x2*)(vr + ((kk * 64 + 32 + g * 8) ^ key));
                union { unsigned u[4]; bf16x8 v; } bv;
                bv.u[0] = vlo[0]; bv.u[1] = vlo[1]; bv.u[2] = vhi[0]; bv.u[3] = vhi[1];
#pragma unroll
                for (int j = 0; j < 3; ++j)
                    O[j][dc] = __builtin_amdgcn_mfma_f32_16x16x32_bf16(af[j], bv.v, O[j][dc], 0, 0, 0);
            }
        }
    };

    EReg EA, EB;
    // prologue: issue-order pinned by empty memory-clobber asm (counts depend on it)
    stage(0, smem[0]);  asm volatile("" ::: "memory");
    eload(EA, 0);       asm volatile("" ::: "memory");
    stage(1, smem[1]);  asm volatile("" ::: "memory");
    eload(EB, 1);       asm volatile("" ::: "memory");

#define PH_FULL(kk, EX, STT, VMS)                                          \
    {                                                                      \
        asm volatile("s_waitcnt vmcnt(" VMS ")" ::: "memory");             \
        __builtin_amdgcn_s_barrier();                                      \
        __builtin_amdgcn_sched_barrier(0);                                 \
        unsigned rr[4][3][2];                                              \
        stage(STT, smem[(kk + 2) & 3]);  asm volatile("" ::: "memory");    \
        computeS(smem[kk], EX, rr);                                        \
        eload(EX, STT);                  asm volatile("" ::: "memory");    \
        computePV(smem[kk], rr);                                           \
    }
#define PH_TAIL(kk, EX, VMS)                                               \
    {                                                                      \
        asm volatile("s_waitcnt vmcnt(" VMS ")" ::: "memory");             \
        __builtin_amdgcn_s_barrier();                                      \
        __builtin_amdgcn_sched_barrier(0);                                 \
        unsigned rr[4][3][2];                                              \
        computeS(smem[kk], EX, rr);                                        \
        computePV(smem[kk], rr);                                           \
    }

#pragma unroll 1
    for (int t = 0; t < 12; t += 4) {
        PH_FULL(0, EA, t + 2, "12")
        PH_FULL(1, EB, t + 3, "12")
        PH_FULL(2, EA, t + 4, "12")
        PH_FULL(3, EB, t + 5, "12")
    }
    // peeled final iteration (tiles 12..15): stages 14,15 then none
    PH_FULL(0, EA, 14, "12")
    PH_FULL(1, EB, 15, "12")
    PH_TAIL(2, EA, "12")
    PH_TAIL(3, EB, "4")
#undef PH_FULL
#undef PH_TAIL

    // reduce lsum over g-groups (k partitioned across g)
    lsum0 += __shfl_xor(lsum0, 16); lsum0 += __shfl_xor(lsum0, 32);
    lsum1 += __shfl_xor(lsum1, 16); lsum1 += __shfl_xor(lsum1, 32);
    lsum2 += __shfl_xor(lsum2, 16); lsum2 += __shfl_xor(lsum2, 32);

    float b0 = beta[0], b1 = beta[1], b2 = beta[2];
    float bm = fmaxf(b0, fmaxf(b1, b2));
    float e0 = __expf(b0 - bm), e1 = __expf(b1 - bm), e2 = __expf(b2 - bm);
    float inv = 1.0f / (e0 + e1 + e2);
    float i0 = e0 * inv / lsum0, i1 = e1 * inv / lsum1, i2 = e2 * inv / lsum2;

    // lane (c,g) holds O rows q=4g+ii, cols d=dc*16+c; fetch per-row 1/lsum from lane q
    float iq0[4], iq1[4], iq2[4];
#pragma unroll
    for (int ii = 0; ii < 4; ++ii) {
        iq0[ii] = __shfl(i0, g * 4 + ii);
        iq1[ii] = __shfl(i1, g * 4 + ii);
        iq2[ii] = __shfl(i2, g * 4 + ii);
    }
    const int hcol = (bh & 7) * 64;
#pragma unroll
    for (int dc = 0; dc < 4; ++dc) {
#pragma unroll
        for (int ii = 0; ii < 4; ++ii) {
            float hv = iq0[ii] * O[0][dc][ii] + iq1[ii] * O[1][dc][ii] + iq2[ii] * O[2][dc][ii];
            int qrow = q0 + g * 4 + ii;
            hb[((size_t)(b << 10) + qrow) * C_ + hcol + dc * 16 + c] = f2bf(hv);
        }
    }
}

extern "C" void kernel_launch(void* const* d_in, const int* in_sizes, int n_in,
                              void* d_out, int out_size, void* d_ws, size_t ws_size,
                              hipStream_t stream) {
    const float* x          = (const float*)d_in[0];
    const float* adj        = (const float*)d_in[1];
    const float* wqkv       = (const float*)d_in[2];
    const float* wproj      = (const float*)d_in[3];
    const float* bias_scale = (const float*)d_in[4];
    const float* beta       = (const float*)d_in[5];
    float* out = (float*)d_out;

    char* ws = (char*)d_ws;
    size_t off = 0;
    auto alloc = [&](size_t bytes) {
        void* p = ws + off;
        off += (bytes + 255) & ~(size_t)255;
        return p;
    };
    unsigned short* wqkvb  = (unsigned short*)alloc((size_t)3 * C_ * C_ * 2);
    unsigned short* wprojb = (unsigned short*)alloc((size_t)C_ * C_ * 2);
    unsigned short* Qb     = (unsigned short*)alloc((size_t)BH_ * L_ * D_ * 2);
    unsigned short* Kb     = (unsigned short*)alloc((size_t)BH_ * L_ * D_ * 2);
    unsigned short* Vtb    = (unsigned short*)alloc((size_t)BH_ * D_ * L_ * 2);
    unsigned short* EI     = (unsigned short*)alloc((size_t)B_ * L_ * L_ * 4);  // ef+eb: B*L*L*2 bf16
    unsigned short* hb     = (unsigned short*)alloc((size_t)M_ * C_ * 2);

    cvt_w<<<(NWQ4 + NWP4 + 255) / 256, 256, 0, stream>>>(wqkv, wproj, wqkvb, wprojb);
    prep_e<<<dim3(16, 16, B_), 256, 0, stream>>>(adj, bias_scale, EI);
    gemm_bf16<64, 128, 512, 0, 0, true><<<dim3(1536 / 128, M_ / 64), 256, 0, stream>>>(nullptr, x, wqkvb, nullptr, Qb, Kb, Vtb);
    attn_kernel<<<dim3(512), 256, 0, stream>>>(Qb, Kb, Vtb, EI, beta, hb);
    gemm_bf16<64, 64, 512, 1, 512, false><<<dim3(512 / 64, M_ / 64), 256, 0, stream>>>(hb, nullptr, wprojb, out, nullptr, nullptr, nullptr);
}

// Round 8
// 78.562 us; speedup vs baseline: 1.4455x; 1.4455x over previous
//
#include <hip/hip_runtime.h>
#include <hip/hip_bf16.h>
#include <stdint.h>

#define B_  4
#define L_  1024
#define C_  512
#define D_  64
#define BH_ 32
#define M_  4096

typedef short  bf16x8 __attribute__((ext_vector_type(8)));
typedef float  f32x4  __attribute__((ext_vector_type(4)));
typedef unsigned short u16x8 __attribute__((ext_vector_type(8)));
typedef unsigned int   u32x2 __attribute__((ext_vector_type(2)));

__device__ __forceinline__ unsigned short f2bf(float f) {
    union { float f; uint32_t u; } v; v.f = f;
    uint32_t u = v.u;
    return (unsigned short)((u + 0x7fffu + ((u >> 16) & 1u)) >> 16);
}
__device__ __forceinline__ float bf2f(unsigned short s) {
    union { uint32_t u; float f; } v; v.u = ((uint32_t)s) << 16;
    return v.f;
}

// async global->LDS, 16B per lane; LDS dest = wave-uniform base (+ implicit lane*16)
__device__ __forceinline__ void gload16(const void* g, void* s) {
    __builtin_amdgcn_global_load_lds((const __attribute__((address_space(1))) void*)g,
                                     (__attribute__((address_space(3))) void*)s, 16, 0, 0);
}

// ---------------- f32 -> bf16 convert (weights only; x fused into qkv GEMM) ----------------
#define NWQ4  (3 * C_ * C_ / 4)        // 196608
#define NWP4  (C_ * C_ / 4)            // 65536
__global__ void cvt_w(const float* __restrict__ wq, const float* __restrict__ wp,
                      unsigned short* __restrict__ wqb, unsigned short* __restrict__ wpb) {
    int i = blockIdx.x * 256 + threadIdx.x;
    const float* src; unsigned short* dst; int o;
    if (i < NWQ4) { src = wq; dst = wqb; o = i; }
    else if (i < NWQ4 + NWP4) { src = wp; dst = wpb; o = i - NWQ4; }
    else return;
    float4 v = ((const float4*)src)[o];
    ushort4 r;
    r.x = f2bf(v.x); r.y = f2bf(v.y); r.z = f2bf(v.z); r.w = f2bf(v.w);
    ((ushort4*)dst)[o] = r;
}

// ---------------- precompute E = exp(bias), symmetric-pair blocks ----------------
// EI layout: [b][q16(64)][k16(64)][lane(64)][ef x4 | eb x4] bf16 (16B per lane).
// lane l=(c,g), elem e: q = q16*16 + c, k = k16*16 + 4g + e.
__global__ __launch_bounds__(256) void prep_e(const float* __restrict__ adj,
                                              const float* __restrict__ bias_scale,
                                              unsigned short* __restrict__ EI) {
    const int bI = blockIdx.z;
    const int i = blockIdx.y, j = blockIdx.x;
    if (j < i) return;
    __shared__ float Ta[64][68];   // adj[i-rows][j-cols]
    __shared__ float Tb[64][68];   // adj[j-rows][i-cols]
    const float* adjb = adj + (size_t)bI * L_ * L_;
    const int tid = threadIdx.x;
#pragma unroll
    for (int s = 0; s < 4; ++s) {
        int idx = s * 256 + tid;
        int r = idx >> 4, c4 = (idx & 15) * 4;
        float4 va = *(const float4*)(adjb + (size_t)(i * 64 + r) * L_ + j * 64 + c4);
        float4 vb = *(const float4*)(adjb + (size_t)(j * 64 + r) * L_ + i * 64 + c4);
        *(float4*)&Ta[r][c4] = va;
        *(float4*)&Tb[r][c4] = vb;
    }
    __syncthreads();
    const float bs0 = bias_scale[0], bs1 = bias_scale[1];
    const int w = tid >> 6, l = tid & 63, g = l >> 4, c = l & 15;
    const int kloc = w * 16 + g * 4;
#pragma unroll
    for (int qs = 0; qs < 4; ++qs) {
        const int qloc = qs * 16 + c;
        {   // tile (qb=i, kb=j)
            int qg = i * 64 + qloc, kgb = j * 64 + kloc;
            unsigned short ef[4], eb[4];
#pragma unroll
            for (int e = 0; e < 4; ++e) {
                bool z = (qg == 0) || (kgb + e == 0);
                ef[e] = f2bf(z ? 1.0f : __expf(bs0 * Ta[qloc][kloc + e]));
                eb[e] = f2bf(z ? 1.0f : __expf(bs1 * Tb[kloc + e][qloc]));
            }
            size_t o = (((size_t)bI * 64 + (i * 4 + qs)) * 64 + (j * 4 + w)) * 512 + (size_t)l * 8;
            *(u16x8*)(EI + o) = (u16x8){ef[0], ef[1], ef[2], ef[3], eb[0], eb[1], eb[2], eb[3]};
        }
        if (i != j) {  // mirrored tile (qb=j, kb=i)
            int qg = j * 64 + qloc, kgb = i * 64 + kloc;
            unsigned short ef[4], eb[4];
#pragma unroll
            for (int e = 0; e < 4; ++e) {
                bool z = (qg == 0) || (kgb + e == 0);
                ef[e] = f2bf(z ? 1.0f : __expf(bs0 * Tb[qloc][kloc + e]));
                eb[e] = f2bf(z ? 1.0f : __expf(bs1 * Ta[kloc + e][qloc]));
            }
            size_t o = (((size_t)bI * 64 + (j * 4 + qs)) * 64 + (i * 4 + w)) * 512 + (size_t)l * 8;
            *(u16x8*)(EI + o) = (u16x8){ef[0], ef[1], ef[2], ef[3], eb[0], eb[1], eb[2], eb[3]};
        }
    }
}

// ---------------- bf16 MFMA GEMM: out[M,N] = A[M,K] * B[N,K]^T ----------------
template <int BM, int BN, int KDIM, int EPI, int NDIM, bool AF32>
__global__ __launch_bounds__(256, 4) void gemm_bf16(const unsigned short* __restrict__ Amat,
                                                    const float* __restrict__ Af,
                                                    const unsigned short* __restrict__ Bmat,
                                                    float* __restrict__ outp,
                                                    unsigned short* __restrict__ q_out,
                                                    unsigned short* __restrict__ k_out,
                                                    unsigned short* __restrict__ v_out) {
    constexpr int NA = BM / 32, NB = BN / 32;
    constexpr int MI = BM / 32, NI = BN / 32;
    __shared__ __align__(16) unsigned short As[BM * 64];
    __shared__ __align__(16) unsigned short Bs[BN * 64];
    const int tid = threadIdx.x;
    const int l = tid & 63, wid = tid >> 6;
    const int g = l >> 4, c = l & 15;
    const int wr = wid >> 1, wc = wid & 1;
    const int row0 = blockIdx.y * BM, col0 = blockIdx.x * BN;

    f32x4 acc[MI][NI];
#pragma unroll
    for (int mi = 0; mi < MI; ++mi)
#pragma unroll
        for (int ni = 0; ni < NI; ++ni) acc[mi][ni] = (f32x4){0.f, 0.f, 0.f, 0.f};

    for (int k0 = 0; k0 < KDIM; k0 += 64) {
        bf16x8 ra[NA], rb[NB];
#pragma unroll
        for (int i = 0; i < NA; ++i) {
            int q = i * 256 + tid;
            int r = q >> 3;
            if constexpr (AF32) {
                const float* ap = Af + (size_t)(row0 + r) * KDIM + k0 + (q & 7) * 8;
                float4 v0 = *(const float4*)ap;
                float4 v1 = *(const float4*)(ap + 4);
                union { unsigned short s[8]; bf16x8 v; } u;
                u.s[0] = f2bf(v0.x); u.s[1] = f2bf(v0.y); u.s[2] = f2bf(v0.z); u.s[3] = f2bf(v0.w);
                u.s[4] = f2bf(v1.x); u.s[5] = f2bf(v1.y); u.s[6] = f2bf(v1.z); u.s[7] = f2bf(v1.w);
                ra[i] = u.v;
            } else {
                ra[i] = *(const bf16x8*)((const char*)Amat + (size_t)(row0 + r) * (KDIM * 2) + k0 * 2 + (q & 7) * 16);
            }
        }
#pragma unroll
        for (int i = 0; i < NB; ++i) {
            int q = i * 256 + tid;
            int r = q >> 3, cb = (q & 7) * 16;
            rb[i] = *(const bf16x8*)((const char*)Bmat + (size_t)(col0 + r) * (KDIM * 2) + k0 * 2 + cb);
        }
        __syncthreads();
#pragma unroll
        for (int i = 0; i < NA; ++i) {
            int q = i * 256 + tid;
            int r = q >> 3, cb = (q & 7) * 16;
            *(bf16x8*)((char*)As + r * 128 + (cb ^ ((r & 7) << 4))) = ra[i];
        }
#pragma unroll
        for (int i = 0; i < NB; ++i) {
            int q = i * 256 + tid;
            int r = q >> 3, cb = (q & 7) * 16;
            *(bf16x8*)((char*)Bs + r * 128 + (cb ^ ((r & 7) << 4))) = rb[i];
        }
        __syncthreads();
#pragma unroll
        for (int kk = 0; kk < 2; ++kk) {
            bf16x8 afr[MI], bfr[NI];
#pragma unroll
            for (int mi = 0; mi < MI; ++mi) {
                int r = wr * (BM / 2) + mi * 16 + c;
                afr[mi] = *(const bf16x8*)((const char*)As + r * 128 + ((kk * 64 + g * 16) ^ ((r & 7) << 4)));
            }
#pragma unroll
            for (int ni = 0; ni < NI; ++ni) {
                int r = wc * (BN / 2) + ni * 16 + c;
                bfr[ni] = *(const bf16x8*)((const char*)Bs + r * 128 + ((kk * 64 + g * 16) ^ ((r & 7) << 4)));
            }
#pragma unroll
            for (int mi = 0; mi < MI; ++mi)
#pragma unroll
                for (int ni = 0; ni < NI; ++ni)
                    acc[mi][ni] = __builtin_amdgcn_mfma_f32_16x16x32_bf16(afr[mi], bfr[ni], acc[mi][ni], 0, 0, 0);
        }
    }
#pragma unroll
    for (int mi = 0; mi < MI; ++mi) {
#pragma unroll
        for (int ni = 0; ni < NI; ++ni) {
#pragma unroll
            for (int ii = 0; ii < 4; ++ii) {
                int m = row0 + wr * (BM / 2) + mi * 16 + g * 4 + ii;
                int n = col0 + wc * (BN / 2) + ni * 16 + c;
                float val = acc[mi][ni][ii];
                if (EPI == 0) {
                    unsigned short v = f2bf(val);
                    int b = m >> 10, ll = m & 1023;
                    int which = n >> 9, cc = n & 511;
                    int hh = cc >> 6, d = cc & 63;
                    int bh = b * 8 + hh;
                    if (which == 0)      q_out[((size_t)bh * L_ + ll) * D_ + d] = v;
                    else if (which == 1) k_out[((size_t)bh * L_ + ll) * D_ + d] = v;
                    else                 v_out[((size_t)bh * D_ + d) * L_ + ll] = v;
                } else {
                    outp[(size_t)m * NDIM + n] = val;
                }
            }
        }
    }
}

// ---------------- fused 3-branch attention: 2-phase double buffer, all staging via gload_lds ----------------
// Round-6 structure (known good) + E staged through LDS (issue can't sink; latency rides
// the barrier like K/V) + s_setprio around the PV MFMA cluster.
__global__ __launch_bounds__(256, 2) void attn_kernel(const unsigned short* __restrict__ Qb,
                                                      const unsigned short* __restrict__ Kb,
                                                      const unsigned short* __restrict__ Vtb,
                                                      const unsigned short* __restrict__ EI,
                                                      const float* __restrict__ beta,
                                                      unsigned short* __restrict__ hb) {
    // per buffer (32KB): K tile 8KB | V tile 8KB | E 4 waves x 4KB
    __shared__ __align__(16) char smem[2][32768];
    const int tid = threadIdx.x;
    const int w = tid >> 6, l = tid & 63;
    const int g = l >> 4, c = l & 15;

    // XCD-grouping swizzle: 8 head-blocks sharing one (b,q64) EI slice -> same XCD.
    const int p = blockIdx.x;                 // 0..511
    const int s = (p & 7) + 8 * (p >> 6);     // (b, qb) index 0..63
    const int h = (p >> 3) & 7;
    const int b = s >> 4, qb = s & 15;
    const int bh = b * 8 + h;
    const int q0 = qb * 64 + w * 16;
    const int qt = qb * 4 + w;

    const unsigned short* Qrow = Qb + ((size_t)bh * L_ + q0 + c) * D_;
    const bf16x8 qf0 = *(const bf16x8*)(Qrow + g * 8);
    const bf16x8 qf1 = *(const bf16x8*)(Qrow + 32 + g * 8);

    const unsigned short* Kbase = Kb + (size_t)bh * L_ * D_;   // row stride 64
    const unsigned short* Vbase = Vtb + (size_t)bh * D_ * L_;  // row stride 1024
    const unsigned short* Ebase = EI + ((size_t)(b * 64 + qt) * 64) * 512;

    f32x4 O[3][4];
#pragma unroll
    for (int j = 0; j < 3; ++j)
#pragma unroll
        for (int dc = 0; dc < 4; ++dc) O[j][dc] = (f32x4){0.f, 0.f, 0.f, 0.f};
    float lsum0 = 0.f, lsum1 = 0.f, lsum2 = 0.f;

    const int srow = l >> 3, sm = l & 7;       // staging row-within-8, chunk
    const int key = (c & 7) << 4;              // read-side swizzle key

    auto stage = [&](int t, char* base) {
#pragma unroll
        for (int n = 0; n < 2; ++n) {
            int i = 2 * w + n;
            int row = i * 8 + srow;
            int sw = (sm ^ (row & 7)) * 8;     // pre-swizzled global source
            gload16(Kbase + (size_t)(t * 64 + row) * D_ + sw, base + i * 1024);
            gload16(Vbase + (size_t)row * L_ + t * 64 + sw, base + 8192 + i * 1024);
        }
        // E: 4 instrs/wave, linear dest (wave-uniform base, implicit lane*16)
#pragma unroll
        for (int ks = 0; ks < 4; ++ks)
            gload16(Ebase + (size_t)(t * 4 + ks) * 512 + l * 8, base + 16384 + w * 4096 + ks * 1024);
    };

    auto compute = [&](const char* base) {
        const char* Kl = base;
        const char* Vl = base + 8192;
        const char* El = base + 16384 + w * 4096;
        bf16x8 efr[4];
#pragma unroll
        for (int ks = 0; ks < 4; ++ks) efr[ks] = *(const bf16x8*)(El + ks * 1024 + l * 16);

        unsigned rr[4][3][2];
#pragma unroll
        for (int st = 0; st < 4; ++st) {
            const char* kr = Kl + (st * 16 + c) * 128;
            bf16x8 ka = *(const bf16x8*)(kr + ((g * 16) ^ key));
            bf16x8 kb = *(const bf16x8*)(kr + ((64 + g * 16) ^ key));
            f32x4 sacc = (f32x4){0.f, 0.f, 0.f, 0.f};
            sacc = __builtin_amdgcn_mfma_f32_16x16x32_bf16(ka, qf0, sacc, 0, 0, 0);
            sacc = __builtin_amdgcn_mfma_f32_16x16x32_bf16(kb, qf1, sacc, 0, 0, 0);
            float pv[3][4];
#pragma unroll
            for (int i = 0; i < 4; ++i) {
                float p0 = __expf(sacc[i] * 0.125f);
                float p1 = p0 * bf2f((unsigned short)efr[st][i]);
                float p2 = p0 * bf2f((unsigned short)efr[st][4 + i]);
                lsum0 += p0; lsum1 += p1; lsum2 += p2;
                pv[0][i] = p0; pv[1][i] = p1; pv[2][i] = p2;
            }
#pragma unroll
            for (int j = 0; j < 3; ++j) {
                rr[st][j][0] = __builtin_amdgcn_perm(__float_as_uint(pv[j][1]), __float_as_uint(pv[j][0]), 0x07060302u);
                rr[st][j][1] = __builtin_amdgcn_perm(__float_as_uint(pv[j][3]), __float_as_uint(pv[j][2]), 0x07060302u);
            }
        }
#pragma unroll
        for (int kk = 0; kk < 2; ++kk) {
            bf16x8 af[3];
#pragma unroll
            for (int j = 0; j < 3; ++j) {
                union { unsigned u[4]; bf16x8 v; } t_;
                t_.u[0] = rr[2 * kk][j][0];     t_.u[1] = rr[2 * kk][j][1];
                t_.u[2] = rr[2 * kk + 1][j][0]; t_.u[3] = rr[2 * kk + 1][j][1];
                af[j] = t_.v;
            }
            __builtin_amdgcn_s_setprio(1);
#pragma unroll
            for (int dc = 0; dc < 4; ++dc) {
                const char* vr = Vl + (dc * 16 + c) * 128;
                u32x2 vlo = *(const u32x2*)(vr + ((kk * 64 + g * 8) ^ key));
                u32x2 vhi = *(const u32x2*)(vr + ((kk * 64 + 32 + g * 8) ^ key));
                union { unsigned u[4]; bf16x8 v; } bv;
                bv.u[0] = vlo[0]; bv.u[1] = vlo[1]; bv.u[2] = vhi[0]; bv.u[3] = vhi[1];
#pragma unroll
                for (int j = 0; j < 3; ++j)
                    O[j][dc] = __builtin_amdgcn_mfma_f32_16x16x32_bf16(af[j], bv.v, O[j][dc], 0, 0, 0);
            }
            __builtin_amdgcn_s_setprio(0);
        }
    };

    stage(0, smem[0]);
    __syncthreads();
#pragma unroll 1
    for (int t = 0; t < 16; t += 2) {
        stage(t + 1, smem[1]);
        compute(smem[0]);
        __syncthreads();
        if (t + 2 < 16) stage(t + 2, smem[0]);
        compute(smem[1]);
        __syncthreads();
    }

    // reduce lsum over g-groups (k partitioned across g)
    lsum0 += __shfl_xor(lsum0, 16); lsum0 += __shfl_xor(lsum0, 32);
    lsum1 += __shfl_xor(lsum1, 16); lsum1 += __shfl_xor(lsum1, 32);
    lsum2 += __shfl_xor(lsum2, 16); lsum2 += __shfl_xor(lsum2, 32);

    float b0 = beta[0], b1 = beta[1], b2 = beta[2];
    float bm = fmaxf(b0, fmaxf(b1, b2));
    float e0 = __expf(b0 - bm), e1 = __expf(b1 - bm), e2 = __expf(b2 - bm);
    float inv = 1.0f / (e0 + e1 + e2);
    float i0 = e0 * inv / lsum0, i1 = e1 * inv / lsum1, i2 = e2 * inv / lsum2;

    float iq0[4], iq1[4], iq2[4];
#pragma unroll
    for (int ii = 0; ii < 4; ++ii) {
        iq0[ii] = __shfl(i0, g * 4 + ii);
        iq1[ii] = __shfl(i1, g * 4 + ii);
        iq2[ii] = __shfl(i2, g * 4 + ii);
    }
    const int hcol = (bh & 7) * 64;
#pragma unroll
    for (int dc = 0; dc < 4; ++dc) {
#pragma unroll
        for (int ii = 0; ii < 4; ++ii) {
            float hv = iq0[ii] * O[0][dc][ii] + iq1[ii] * O[1][dc][ii] + iq2[ii] * O[2][dc][ii];
            int qrow = q0 + g * 4 + ii;
            hb[((size_t)(b << 10) + qrow) * C_ + hcol + dc * 16 + c] = f2bf(hv);
        }
    }
}

extern "C" void kernel_launch(void* const* d_in, const int* in_sizes, int n_in,
                              void* d_out, int out_size, void* d_ws, size_t ws_size,
                              hipStream_t stream) {
    const float* x          = (const float*)d_in[0];
    const float* adj        = (const float*)d_in[1];
    const float* wqkv       = (const float*)d_in[2];
    const float* wproj      = (const float*)d_in[3];
    const float* bias_scale = (const float*)d_in[4];
    const float* beta       = (const float*)d_in[5];
    float* out = (float*)d_out;

    char* ws = (char*)d_ws;
    size_t off = 0;
    auto alloc = [&](size_t bytes) {
        void* p = ws + off;
        off += (bytes + 255) & ~(size_t)255;
        return p;
    };
    unsigned short* wqkvb  = (unsigned short*)alloc((size_t)3 * C_ * C_ * 2);
    unsigned short* wprojb = (unsigned short*)alloc((size_t)C_ * C_ * 2);
    unsigned short* Qb     = (unsigned short*)alloc((size_t)BH_ * L_ * D_ * 2);
    unsigned short* Kb     = (unsigned short*)alloc((size_t)BH_ * L_ * D_ * 2);
    unsigned short* Vtb    = (unsigned short*)alloc((size_t)BH_ * D_ * L_ * 2);
    unsigned short* EI     = (unsigned short*)alloc((size_t)B_ * L_ * L_ * 4);  // ef+eb: B*L*L*2 bf16
    unsigned short* hb     = (unsigned short*)alloc((size_t)M_ * C_ * 2);

    cvt_w<<<(NWQ4 + NWP4 + 255) / 256, 256, 0, stream>>>(wqkv, wproj, wqkvb, wprojb);
    prep_e<<<dim3(16, 16, B_), 256, 0, stream>>>(adj, bias_scale, EI);
    gemm_bf16<64, 128, 512, 0, 0, true><<<dim3(1536 / 128, M_ / 64), 256, 0, stream>>>(nullptr, x, wqkvb, nullptr, Qb, Kb, Vtb);
    attn_kernel<<<dim3(512), 256, 0, stream>>>(Qb, Kb, Vtb, EI, beta, hb);
    gemm_bf16<64, 64, 512, 1, 512, false><<<dim3(512 / 64, M_ / 64), 256, 0, stream>>>(hb, nullptr, wprojb, out, nullptr, nullptr, nullptr);
}

// Round 9
// 78.297 us; speedup vs baseline: 1.4504x; 1.0034x over previous
//
#include <hip/hip_runtime.h>
#include <hip/hip_bf16.h>
#include <stdint.h>

#define B_  4
#define L_  1024
#define C_  512
#define D_  64
#define BH_ 32
#define M_  4096

typedef short  bf16x8 __attribute__((ext_vector_type(8)));
typedef float  f32x4  __attribute__((ext_vector_type(4)));
typedef unsigned short u16x8 __attribute__((ext_vector_type(8)));
typedef unsigned int   u32x2 __attribute__((ext_vector_type(2)));

__device__ __forceinline__ unsigned short f2bf(float f) {
    union { float f; uint32_t u; } v; v.f = f;
    uint32_t u = v.u;
    return (unsigned short)((u + 0x7fffu + ((u >> 16) & 1u)) >> 16);
}
__device__ __forceinline__ float bf2f(unsigned short s) {
    union { uint32_t u; float f; } v; v.u = ((uint32_t)s) << 16;
    return v.f;
}

// async global->LDS, 16B per lane; LDS dest = wave-uniform base (+ implicit lane*16)
__device__ __forceinline__ void gload16(const void* g, void* s) {
    __builtin_amdgcn_global_load_lds((const __attribute__((address_space(1))) void*)g,
                                     (__attribute__((address_space(3))) void*)s, 16, 0, 0);
}

// ---------------- f32 -> bf16 convert (weights only; x fused into qkv GEMM) ----------------
#define NWQ4  (3 * C_ * C_ / 4)        // 196608
#define NWP4  (C_ * C_ / 4)            // 65536
__global__ void cvt_w(const float* __restrict__ wq, const float* __restrict__ wp,
                      unsigned short* __restrict__ wqb, unsigned short* __restrict__ wpb) {
    int i = blockIdx.x * 256 + threadIdx.x;
    const float* src; unsigned short* dst; int o;
    if (i < NWQ4) { src = wq; dst = wqb; o = i; }
    else if (i < NWQ4 + NWP4) { src = wp; dst = wpb; o = i - NWQ4; }
    else return;
    float4 v = ((const float4*)src)[o];
    ushort4 r;
    r.x = f2bf(v.x); r.y = f2bf(v.y); r.z = f2bf(v.z); r.w = f2bf(v.w);
    ((ushort4*)dst)[o] = r;
}

// ---------------- precompute E = exp(bias), symmetric-pair blocks ----------------
// EI layout: [b][q16(64)][k16(64)][lane(64)][ef x4 | eb x4] bf16 (16B per lane).
// lane l=(c,g), elem e: q = q16*16 + c, k = k16*16 + 4g + e.
__global__ __launch_bounds__(256) void prep_e(const float* __restrict__ adj,
                                              const float* __restrict__ bias_scale,
                                              unsigned short* __restrict__ EI) {
    const int bI = blockIdx.z;
    const int i = blockIdx.y, j = blockIdx.x;
    if (j < i) return;
    __shared__ float Ta[64][68];   // adj[i-rows][j-cols]
    __shared__ float Tb[64][68];   // adj[j-rows][i-cols]
    const float* adjb = adj + (size_t)bI * L_ * L_;
    const int tid = threadIdx.x;
#pragma unroll
    for (int s = 0; s < 4; ++s) {
        int idx = s * 256 + tid;
        int r = idx >> 4, c4 = (idx & 15) * 4;
        float4 va = *(const float4*)(adjb + (size_t)(i * 64 + r) * L_ + j * 64 + c4);
        float4 vb = *(const float4*)(adjb + (size_t)(j * 64 + r) * L_ + i * 64 + c4);
        *(float4*)&Ta[r][c4] = va;
        *(float4*)&Tb[r][c4] = vb;
    }
    __syncthreads();
    const float bs0 = bias_scale[0], bs1 = bias_scale[1];
    const int w = tid >> 6, l = tid & 63, g = l >> 4, c = l & 15;
    const int kloc = w * 16 + g * 4;
#pragma unroll
    for (int qs = 0; qs < 4; ++qs) {
        const int qloc = qs * 16 + c;
        {   // tile (qb=i, kb=j)
            int qg = i * 64 + qloc, kgb = j * 64 + kloc;
            unsigned short ef[4], eb[4];
#pragma unroll
            for (int e = 0; e < 4; ++e) {
                bool z = (qg == 0) || (kgb + e == 0);
                ef[e] = f2bf(z ? 1.0f : __expf(bs0 * Ta[qloc][kloc + e]));
                eb[e] = f2bf(z ? 1.0f : __expf(bs1 * Tb[kloc + e][qloc]));
            }
            size_t o = (((size_t)bI * 64 + (i * 4 + qs)) * 64 + (j * 4 + w)) * 512 + (size_t)l * 8;
            *(u16x8*)(EI + o) = (u16x8){ef[0], ef[1], ef[2], ef[3], eb[0], eb[1], eb[2], eb[3]};
        }
        if (i != j) {  // mirrored tile (qb=j, kb=i)
            int qg = j * 64 + qloc, kgb = i * 64 + kloc;
            unsigned short ef[4], eb[4];
#pragma unroll
            for (int e = 0; e < 4; ++e) {
                bool z = (qg == 0) || (kgb + e == 0);
                ef[e] = f2bf(z ? 1.0f : __expf(bs0 * Tb[qloc][kloc + e]));
                eb[e] = f2bf(z ? 1.0f : __expf(bs1 * Ta[kloc + e][qloc]));
            }
            size_t o = (((size_t)bI * 64 + (j * 4 + qs)) * 64 + (i * 4 + w)) * 512 + (size_t)l * 8;
            *(u16x8*)(EI + o) = (u16x8){ef[0], ef[1], ef[2], ef[3], eb[0], eb[1], eb[2], eb[3]};
        }
    }
}

// ---------------- bf16 MFMA GEMM: out[M,N] = A[M,K] * B[N,K]^T ----------------
template <int BM, int BN, int KDIM, int EPI, int NDIM, bool AF32>
__global__ __launch_bounds__(256, 4) void gemm_bf16(const unsigned short* __restrict__ Amat,
                                                    const float* __restrict__ Af,
                                                    const unsigned short* __restrict__ Bmat,
                                                    float* __restrict__ outp,
                                                    unsigned short* __restrict__ q_out,
                                                    unsigned short* __restrict__ k_out,
                                                    unsigned short* __restrict__ v_out) {
    constexpr int NA = BM / 32, NB = BN / 32;
    constexpr int MI = BM / 32, NI = BN / 32;
    __shared__ __align__(16) unsigned short As[BM * 64];
    __shared__ __align__(16) unsigned short Bs[BN * 64];
    const int tid = threadIdx.x;
    const int l = tid & 63, wid = tid >> 6;
    const int g = l >> 4, c = l & 15;
    const int wr = wid >> 1, wc = wid & 1;
    const int row0 = blockIdx.y * BM, col0 = blockIdx.x * BN;

    f32x4 acc[MI][NI];
#pragma unroll
    for (int mi = 0; mi < MI; ++mi)
#pragma unroll
        for (int ni = 0; ni < NI; ++ni) acc[mi][ni] = (f32x4){0.f, 0.f, 0.f, 0.f};

    for (int k0 = 0; k0 < KDIM; k0 += 64) {
        bf16x8 ra[NA], rb[NB];
#pragma unroll
        for (int i = 0; i < NA; ++i) {
            int q = i * 256 + tid;
            int r = q >> 3;
            if constexpr (AF32) {
                const float* ap = Af + (size_t)(row0 + r) * KDIM + k0 + (q & 7) * 8;
                float4 v0 = *(const float4*)ap;
                float4 v1 = *(const float4*)(ap + 4);
                union { unsigned short s[8]; bf16x8 v; } u;
                u.s[0] = f2bf(v0.x); u.s[1] = f2bf(v0.y); u.s[2] = f2bf(v0.z); u.s[3] = f2bf(v0.w);
                u.s[4] = f2bf(v1.x); u.s[5] = f2bf(v1.y); u.s[6] = f2bf(v1.z); u.s[7] = f2bf(v1.w);
                ra[i] = u.v;
            } else {
                ra[i] = *(const bf16x8*)((const char*)Amat + (size_t)(row0 + r) * (KDIM * 2) + k0 * 2 + (q & 7) * 16);
            }
        }
#pragma unroll
        for (int i = 0; i < NB; ++i) {
            int q = i * 256 + tid;
            int r = q >> 3, cb = (q & 7) * 16;
            rb[i] = *(const bf16x8*)((const char*)Bmat + (size_t)(col0 + r) * (KDIM * 2) + k0 * 2 + cb);
        }
        __syncthreads();
#pragma unroll
        for (int i = 0; i < NA; ++i) {
            int q = i * 256 + tid;
            int r = q >> 3, cb = (q & 7) * 16;
            *(bf16x8*)((char*)As + r * 128 + (cb ^ ((r & 7) << 4))) = ra[i];
        }
#pragma unroll
        for (int i = 0; i < NB; ++i) {
            int q = i * 256 + tid;
            int r = q >> 3, cb = (q & 7) * 16;
            *(bf16x8*)((char*)Bs + r * 128 + (cb ^ ((r & 7) << 4))) = rb[i];
        }
        __syncthreads();
#pragma unroll
        for (int kk = 0; kk < 2; ++kk) {
            bf16x8 afr[MI], bfr[NI];
#pragma unroll
            for (int mi = 0; mi < MI; ++mi) {
                int r = wr * (BM / 2) + mi * 16 + c;
                afr[mi] = *(const bf16x8*)((const char*)As + r * 128 + ((kk * 64 + g * 16) ^ ((r & 7) << 4)));
            }
#pragma unroll
            for (int ni = 0; ni < NI; ++ni) {
                int r = wc * (BN / 2) + ni * 16 + c;
                bfr[ni] = *(const bf16x8*)((const char*)Bs + r * 128 + ((kk * 64 + g * 16) ^ ((r & 7) << 4)));
            }
#pragma unroll
            for (int mi = 0; mi < MI; ++mi)
#pragma unroll
                for (int ni = 0; ni < NI; ++ni)
                    acc[mi][ni] = __builtin_amdgcn_mfma_f32_16x16x32_bf16(afr[mi], bfr[ni], acc[mi][ni], 0, 0, 0);
        }
    }
#pragma unroll
    for (int mi = 0; mi < MI; ++mi) {
#pragma unroll
        for (int ni = 0; ni < NI; ++ni) {
#pragma unroll
            for (int ii = 0; ii < 4; ++ii) {
                int m = row0 + wr * (BM / 2) + mi * 16 + g * 4 + ii;
                int n = col0 + wc * (BN / 2) + ni * 16 + c;
                float val = acc[mi][ni][ii];
                if (EPI == 0) {
                    unsigned short v = f2bf(val);
                    int b = m >> 10, ll = m & 1023;
                    int which = n >> 9, cc = n & 511;
                    int hh = cc >> 6, d = cc & 63;
                    int bh = b * 8 + hh;
                    if (which == 0)      q_out[((size_t)bh * L_ + ll) * D_ + d] = v;
                    else if (which == 1) k_out[((size_t)bh * L_ + ll) * D_ + d] = v;
                    else                 v_out[((size_t)bh * D_ + d) * L_ + ll] = v;
                } else {
                    outp[(size_t)m * NDIM + n] = val;
                }
            }
        }
    }
}

// ---------------- fused 3-branch attention: round-6 structure (best known) ----------------
// 2-phase __syncthreads double buffer; K/V via global_load_lds; E plain register prefetch.
struct EReg { bf16x8 e[4]; };

__global__ __launch_bounds__(256, 2) void attn_kernel(const unsigned short* __restrict__ Qb,
                                                      const unsigned short* __restrict__ Kb,
                                                      const unsigned short* __restrict__ Vtb,
                                                      const unsigned short* __restrict__ EI,
                                                      const float* __restrict__ beta,
                                                      unsigned short* __restrict__ hb) {
    // per buffer (16KB): K tile 8KB | V tile 8KB
    __shared__ __align__(16) char smem[2][16384];
    const int tid = threadIdx.x;
    const int w = tid >> 6, l = tid & 63;
    const int g = l >> 4, c = l & 15;

    // XCD-grouping swizzle: 8 head-blocks sharing one (b,q64) EI slice -> same XCD.
    const int p = blockIdx.x;                 // 0..511
    const int s = (p & 7) + 8 * (p >> 6);     // (b, qb) index 0..63
    const int h = (p >> 3) & 7;
    const int b = s >> 4, qb = s & 15;
    const int bh = b * 8 + h;
    const int q0 = qb * 64 + w * 16;
    const int qt = qb * 4 + w;

    const unsigned short* Qrow = Qb + ((size_t)bh * L_ + q0 + c) * D_;
    const bf16x8 qf0 = *(const bf16x8*)(Qrow + g * 8);
    const bf16x8 qf1 = *(const bf16x8*)(Qrow + 32 + g * 8);

    const unsigned short* Kbase = Kb + (size_t)bh * L_ * D_;   // row stride 64
    const unsigned short* Vbase = Vtb + (size_t)bh * D_ * L_;  // row stride 1024
    const unsigned short* Ebase = EI + ((size_t)(b * 64 + qt) * 64) * 512;

    f32x4 O[3][4];
#pragma unroll
    for (int j = 0; j < 3; ++j)
#pragma unroll
        for (int dc = 0; dc < 4; ++dc) O[j][dc] = (f32x4){0.f, 0.f, 0.f, 0.f};
    float lsum0 = 0.f, lsum1 = 0.f, lsum2 = 0.f;

    const int srow = l >> 3, sm = l & 7;       // staging row-within-8, chunk
    const int key = (c & 7) << 4;              // read-side swizzle key

    auto stage = [&](int t, char* base) {
#pragma unroll
        for (int n = 0; n < 2; ++n) {
            int i = 2 * w + n;
            int row = i * 8 + srow;
            int sw = (sm ^ (row & 7)) * 8;     // pre-swizzled global source
            gload16(Kbase + (size_t)(t * 64 + row) * D_ + sw, base + i * 1024);
            gload16(Vbase + (size_t)row * L_ + t * 64 + sw, base + 8192 + i * 1024);
        }
    };
    auto eload = [&](EReg& X, int t) {
#pragma unroll
        for (int ks = 0; ks < 4; ++ks)
            X.e[ks] = *(const bf16x8*)(Ebase + (size_t)(t * 4 + ks) * 512 + l * 8);
    };

    auto compute = [&](const char* base, const EReg& E) {
        const char* Kl = base;
        const char* Vl = base + 8192;
        unsigned rr[4][3][2];
#pragma unroll
        for (int st = 0; st < 4; ++st) {
            const char* kr = Kl + (st * 16 + c) * 128;
            bf16x8 ka = *(const bf16x8*)(kr + ((g * 16) ^ key));
            bf16x8 kb = *(const bf16x8*)(kr + ((64 + g * 16) ^ key));
            f32x4 sacc = (f32x4){0.f, 0.f, 0.f, 0.f};
            sacc = __builtin_amdgcn_mfma_f32_16x16x32_bf16(ka, qf0, sacc, 0, 0, 0);
            sacc = __builtin_amdgcn_mfma_f32_16x16x32_bf16(kb, qf1, sacc, 0, 0, 0);
            float pv[3][4];
#pragma unroll
            for (int i = 0; i < 4; ++i) {
                float p0 = __expf(sacc[i] * 0.125f);
                float p1 = p0 * bf2f((unsigned short)E.e[st][i]);
                float p2 = p0 * bf2f((unsigned short)E.e[st][4 + i]);
                lsum0 += p0; lsum1 += p1; lsum2 += p2;
                pv[0][i] = p0; pv[1][i] = p1; pv[2][i] = p2;
            }
#pragma unroll
            for (int j = 0; j < 3; ++j) {
                rr[st][j][0] = __builtin_amdgcn_perm(__float_as_uint(pv[j][1]), __float_as_uint(pv[j][0]), 0x07060302u);
                rr[st][j][1] = __builtin_amdgcn_perm(__float_as_uint(pv[j][3]), __float_as_uint(pv[j][2]), 0x07060302u);
            }
        }
#pragma unroll
        for (int kk = 0; kk < 2; ++kk) {
            bf16x8 af[3];
#pragma unroll
            for (int j = 0; j < 3; ++j) {
                union { unsigned u[4]; bf16x8 v; } t_;
                t_.u[0] = rr[2 * kk][j][0];     t_.u[1] = rr[2 * kk][j][1];
                t_.u[2] = rr[2 * kk + 1][j][0]; t_.u[3] = rr[2 * kk + 1][j][1];
                af[j] = t_.v;
            }
#pragma unroll
            for (int dc = 0; dc < 4; ++dc) {
                const char* vr = Vl + (dc * 16 + c) * 128;
                u32x2 vlo = *(const u32x2*)(vr + ((kk * 64 + g * 8) ^ key));
                u32x2 vhi = *(const u32x2*)(vr + ((kk * 64 + 32 + g * 8) ^ key));
                union { unsigned u[4]; bf16x8 v; } bv;
                bv.u[0] = vlo[0]; bv.u[1] = vlo[1]; bv.u[2] = vhi[0]; bv.u[3] = vhi[1];
#pragma unroll
                for (int j = 0; j < 3; ++j)
                    O[j][dc] = __builtin_amdgcn_mfma_f32_16x16x32_bf16(af[j], bv.v, O[j][dc], 0, 0, 0);
            }
        }
    };

    EReg E0, E1;
    stage(0, smem[0]);
    eload(E0, 0);
    __syncthreads();
#pragma unroll 1
    for (int t = 0; t < 16; t += 2) {
        stage(t + 1, smem[1]);
        eload(E1, t + 1);
        compute(smem[0], E0);
        __syncthreads();
        if (t + 2 < 16) { stage(t + 2, smem[0]); eload(E0, t + 2); }
        compute(smem[1], E1);
        __syncthreads();
    }

    // reduce lsum over g-groups (k partitioned across g)
    lsum0 += __shfl_xor(lsum0, 16); lsum0 += __shfl_xor(lsum0, 32);
    lsum1 += __shfl_xor(lsum1, 16); lsum1 += __shfl_xor(lsum1, 32);
    lsum2 += __shfl_xor(lsum2, 16); lsum2 += __shfl_xor(lsum2, 32);

    float b0 = beta[0], b1 = beta[1], b2 = beta[2];
    float bm = fmaxf(b0, fmaxf(b1, b2));
    float e0 = __expf(b0 - bm), e1 = __expf(b1 - bm), e2 = __expf(b2 - bm);
    float inv = 1.0f / (e0 + e1 + e2);
    float i0 = e0 * inv / lsum0, i1 = e1 * inv / lsum1, i2 = e2 * inv / lsum2;

    float iq0[4], iq1[4], iq2[4];
#pragma unroll
    for (int ii = 0; ii < 4; ++ii) {
        iq0[ii] = __shfl(i0, g * 4 + ii);
        iq1[ii] = __shfl(i1, g * 4 + ii);
        iq2[ii] = __shfl(i2, g * 4 + ii);
    }
    const int hcol = (bh & 7) * 64;
#pragma unroll
    for (int dc = 0; dc < 4; ++dc) {
#pragma unroll
        for (int ii = 0; ii < 4; ++ii) {
            float hv = iq0[ii] * O[0][dc][ii] + iq1[ii] * O[1][dc][ii] + iq2[ii] * O[2][dc][ii];
            int qrow = q0 + g * 4 + ii;
            hb[((size_t)(b << 10) + qrow) * C_ + hcol + dc * 16 + c] = f2bf(hv);
        }
    }
}

extern "C" void kernel_launch(void* const* d_in, const int* in_sizes, int n_in,
                              void* d_out, int out_size, void* d_ws, size_t ws_size,
                              hipStream_t stream) {
    const float* x          = (const float*)d_in[0];
    const float* adj        = (const float*)d_in[1];
    const float* wqkv       = (const float*)d_in[2];
    const float* wproj      = (const float*)d_in[3];
    const float* bias_scale = (const float*)d_in[4];
    const float* beta       = (const float*)d_in[5];
    float* out = (float*)d_out;

    char* ws = (char*)d_ws;
    size_t off = 0;
    auto alloc = [&](size_t bytes) {
        void* p = ws + off;
        off += (bytes + 255) & ~(size_t)255;
        return p;
    };
    unsigned short* wqkvb  = (unsigned short*)alloc((size_t)3 * C_ * C_ * 2);
    unsigned short* wprojb = (unsigned short*)alloc((size_t)C_ * C_ * 2);
    unsigned short* Qb     = (unsigned short*)alloc((size_t)BH_ * L_ * D_ * 2);
    unsigned short* Kb     = (unsigned short*)alloc((size_t)BH_ * L_ * D_ * 2);
    unsigned short* Vtb    = (unsigned short*)alloc((size_t)BH_ * D_ * L_ * 2);
    unsigned short* EI     = (unsigned short*)alloc((size_t)B_ * L_ * L_ * 4);  // ef+eb: B*L*L*2 bf16
    unsigned short* hb     = (unsigned short*)alloc((size_t)M_ * C_ * 2);

    cvt_w<<<(NWQ4 + NWP4 + 255) / 256, 256, 0, stream>>>(wqkv, wproj, wqkvb, wprojb);
    prep_e<<<dim3(16, 16, B_), 256, 0, stream>>>(adj, bias_scale, EI);
    gemm_bf16<64, 128, 512, 0, 0, true><<<dim3(1536 / 128, M_ / 64), 256, 0, stream>>>(nullptr, x, wqkvb, nullptr, Qb, Kb, Vtb);
    attn_kernel<<<dim3(512), 256, 0, stream>>>(Qb, Kb, Vtb, EI, beta, hb);
    gemm_bf16<64, 64, 512, 1, 512, false><<<dim3(512 / 64, M_ / 64), 256, 0, stream>>>(hb, nullptr, wprojb, out, nullptr, nullptr, nullptr);
}

// Round 10
// 74.344 us; speedup vs baseline: 1.5275x; 1.0532x over previous
//
#include <hip/hip_runtime.h>
#include <hip/hip_bf16.h>
#include <stdint.h>

#define B_  4
#define L_  1024
#define C_  512
#define D_  64
#define BH_ 32
#define M_  4096

typedef short  bf16x8 __attribute__((ext_vector_type(8)));
typedef float  f32x4  __attribute__((ext_vector_type(4)));
typedef unsigned short u16x8 __attribute__((ext_vector_type(8)));
typedef unsigned int   u32x2 __attribute__((ext_vector_type(2)));

__device__ __forceinline__ unsigned short f2bf(float f) {
    union { float f; uint32_t u; } v; v.f = f;
    uint32_t u = v.u;
    return (unsigned short)((u + 0x7fffu + ((u >> 16) & 1u)) >> 16);
}
__device__ __forceinline__ float bf2f(unsigned short s) {
    union { uint32_t u; float f; } v; v.u = ((uint32_t)s) << 16;
    return v.f;
}

// async global->LDS, 16B per lane; LDS dest = wave-uniform base (+ implicit lane*16)
__device__ __forceinline__ void gload16(const void* g, void* s) {
    __builtin_amdgcn_global_load_lds((const __attribute__((address_space(1))) void*)g,
                                     (__attribute__((address_space(3))) void*)s, 16, 0, 0);
}

// ---------------- fused f32 -> bf16 convert for x, W_qkv, W_proj ----------------
#define NX4   (M_ * C_ / 4)            // 524288
#define NWQ4  (3 * C_ * C_ / 4)        // 196608
#define NWP4  (C_ * C_ / 4)            // 65536
__global__ void cvt_all(const float* __restrict__ x, const float* __restrict__ wq,
                        const float* __restrict__ wp,
                        unsigned short* __restrict__ xb, unsigned short* __restrict__ wqb,
                        unsigned short* __restrict__ wpb) {
    int i = blockIdx.x * 256 + threadIdx.x;
    const float* src; unsigned short* dst; int o;
    if (i < NX4) { src = x; dst = xb; o = i; }
    else if (i < NX4 + NWQ4) { src = wq; dst = wqb; o = i - NX4; }
    else if (i < NX4 + NWQ4 + NWP4) { src = wp; dst = wpb; o = i - NX4 - NWQ4; }
    else return;
    float4 v = ((const float4*)src)[o];
    ushort4 r;
    r.x = f2bf(v.x); r.y = f2bf(v.y); r.z = f2bf(v.z); r.w = f2bf(v.w);
    ((ushort4*)dst)[o] = r;
}

// ---------------- precompute E = exp(bias), symmetric-pair blocks ----------------
// EI layout: [b][q16(64)][k16(64)][lane(64)][ef x4 | eb x4] bf16 (16B per lane).
// lane l=(c,g), elem e: q = q16*16 + c, k = k16*16 + 4g + e.
__global__ __launch_bounds__(256) void prep_e(const float* __restrict__ adj,
                                              const float* __restrict__ bias_scale,
                                              unsigned short* __restrict__ EI) {
    const int bI = blockIdx.z;
    const int i = blockIdx.y, j = blockIdx.x;
    if (j < i) return;
    __shared__ float Ta[64][68];   // adj[i-rows][j-cols]
    __shared__ float Tb[64][68];   // adj[j-rows][i-cols]
    const float* adjb = adj + (size_t)bI * L_ * L_;
    const int tid = threadIdx.x;
#pragma unroll
    for (int s = 0; s < 4; ++s) {
        int idx = s * 256 + tid;
        int r = idx >> 4, c4 = (idx & 15) * 4;
        float4 va = *(const float4*)(adjb + (size_t)(i * 64 + r) * L_ + j * 64 + c4);
        float4 vb = *(const float4*)(adjb + (size_t)(j * 64 + r) * L_ + i * 64 + c4);
        *(float4*)&Ta[r][c4] = va;
        *(float4*)&Tb[r][c4] = vb;
    }
    __syncthreads();
    const float bs0 = bias_scale[0], bs1 = bias_scale[1];
    const int w = tid >> 6, l = tid & 63, g = l >> 4, c = l & 15;
    const int kloc = w * 16 + g * 4;
#pragma unroll
    for (int qs = 0; qs < 4; ++qs) {
        const int qloc = qs * 16 + c;
        {   // tile (qb=i, kb=j)
            int qg = i * 64 + qloc, kgb = j * 64 + kloc;
            unsigned short ef[4], eb[4];
#pragma unroll
            for (int e = 0; e < 4; ++e) {
                bool z = (qg == 0) || (kgb + e == 0);
                ef[e] = f2bf(z ? 1.0f : __expf(bs0 * Ta[qloc][kloc + e]));
                eb[e] = f2bf(z ? 1.0f : __expf(bs1 * Tb[kloc + e][qloc]));
            }
            size_t o = (((size_t)bI * 64 + (i * 4 + qs)) * 64 + (j * 4 + w)) * 512 + (size_t)l * 8;
            *(u16x8*)(EI + o) = (u16x8){ef[0], ef[1], ef[2], ef[3], eb[0], eb[1], eb[2], eb[3]};
        }
        if (i != j) {  // mirrored tile (qb=j, kb=i)
            int qg = j * 64 + qloc, kgb = i * 64 + kloc;
            unsigned short ef[4], eb[4];
#pragma unroll
            for (int e = 0; e < 4; ++e) {
                bool z = (qg == 0) || (kgb + e == 0);
                ef[e] = f2bf(z ? 1.0f : __expf(bs0 * Tb[qloc][kloc + e]));
                eb[e] = f2bf(z ? 1.0f : __expf(bs1 * Ta[kloc + e][qloc]));
            }
            size_t o = (((size_t)bI * 64 + (j * 4 + qs)) * 64 + (i * 4 + w)) * 512 + (size_t)l * 8;
            *(u16x8*)(EI + o) = (u16x8){ef[0], ef[1], ef[2], ef[3], eb[0], eb[1], eb[2], eb[3]};
        }
    }
}

// ---------------- bf16 MFMA GEMM: out[M,N] = A[M,K] * B[N,K]^T ----------------
template <int BM, int BN, int KDIM, int EPI, int NDIM>
__global__ __launch_bounds__(256, 4) void gemm_bf16(const unsigned short* __restrict__ Amat,
                                                    const unsigned short* __restrict__ Bmat,
                                                    float* __restrict__ outp,
                                                    unsigned short* __restrict__ q_out,
                                                    unsigned short* __restrict__ k_out,
                                                    unsigned short* __restrict__ v_out) {
    constexpr int NA = BM / 32, NB = BN / 32;
    constexpr int MI = BM / 32, NI = BN / 32;
    __shared__ __align__(16) unsigned short As[BM * 64];
    __shared__ __align__(16) unsigned short Bs[BN * 64];
    const int tid = threadIdx.x;
    const int l = tid & 63, wid = tid >> 6;
    const int g = l >> 4, c = l & 15;
    const int wr = wid >> 1, wc = wid & 1;
    const int row0 = blockIdx.y * BM, col0 = blockIdx.x * BN;

    f32x4 acc[MI][NI];
#pragma unroll
    for (int mi = 0; mi < MI; ++mi)
#pragma unroll
        for (int ni = 0; ni < NI; ++ni) acc[mi][ni] = (f32x4){0.f, 0.f, 0.f, 0.f};

    for (int k0 = 0; k0 < KDIM; k0 += 64) {
        bf16x8 ra[NA], rb[NB];
#pragma unroll
        for (int i = 0; i < NA; ++i) {
            int q = i * 256 + tid;
            int r = q >> 3, cb = (q & 7) * 16;
            ra[i] = *(const bf16x8*)((const char*)Amat + (size_t)(row0 + r) * (KDIM * 2) + k0 * 2 + cb);
        }
#pragma unroll
        for (int i = 0; i < NB; ++i) {
            int q = i * 256 + tid;
            int r = q >> 3, cb = (q & 7) * 16;
            rb[i] = *(const bf16x8*)((const char*)Bmat + (size_t)(col0 + r) * (KDIM * 2) + k0 * 2 + cb);
        }
        __syncthreads();
#pragma unroll
        for (int i = 0; i < NA; ++i) {
            int q = i * 256 + tid;
            int r = q >> 3, cb = (q & 7) * 16;
            *(bf16x8*)((char*)As + r * 128 + (cb ^ ((r & 7) << 4))) = ra[i];
        }
#pragma unroll
        for (int i = 0; i < NB; ++i) {
            int q = i * 256 + tid;
            int r = q >> 3, cb = (q & 7) * 16;
            *(bf16x8*)((char*)Bs + r * 128 + (cb ^ ((r & 7) << 4))) = rb[i];
        }
        __syncthreads();
#pragma unroll
        for (int kk = 0; kk < 2; ++kk) {
            bf16x8 afr[MI], bfr[NI];
#pragma unroll
            for (int mi = 0; mi < MI; ++mi) {
                int r = wr * (BM / 2) + mi * 16 + c;
                afr[mi] = *(const bf16x8*)((const char*)As + r * 128 + ((kk * 64 + g * 16) ^ ((r & 7) << 4)));
            }
#pragma unroll
            for (int ni = 0; ni < NI; ++ni) {
                int r = wc * (BN / 2) + ni * 16 + c;
                bfr[ni] = *(const bf16x8*)((const char*)Bs + r * 128 + ((kk * 64 + g * 16) ^ ((r & 7) << 4)));
            }
#pragma unroll
            for (int mi = 0; mi < MI; ++mi)
#pragma unroll
                for (int ni = 0; ni < NI; ++ni)
                    acc[mi][ni] = __builtin_amdgcn_mfma_f32_16x16x32_bf16(afr[mi], bfr[ni], acc[mi][ni], 0, 0, 0);
        }
    }
#pragma unroll
    for (int mi = 0; mi < MI; ++mi) {
#pragma unroll
        for (int ni = 0; ni < NI; ++ni) {
#pragma unroll
            for (int ii = 0; ii < 4; ++ii) {
                int m = row0 + wr * (BM / 2) + mi * 16 + g * 4 + ii;
                int n = col0 + wc * (BN / 2) + ni * 16 + c;
                float val = acc[mi][ni][ii];
                if (EPI == 0) {
                    unsigned short v = f2bf(val);
                    int b = m >> 10, ll = m & 1023;
                    int which = n >> 9, cc = n & 511;
                    int hh = cc >> 6, d = cc & 63;
                    int bh = b * 8 + hh;
                    if (which == 0)      q_out[((size_t)bh * L_ + ll) * D_ + d] = v;
                    else if (which == 1) k_out[((size_t)bh * L_ + ll) * D_ + d] = v;
                    else                 v_out[((size_t)bh * D_ + d) * L_ + ll] = v;
                } else {
                    outp[(size_t)m * NDIM + n] = val;
                }
            }
        }
    }
}

// ---------------- fused 3-branch attention: round-6 structure (best known) ----------------
// 2-phase __syncthreads double buffer; K/V via global_load_lds; E plain register prefetch.
struct EReg { bf16x8 e[4]; };

__global__ __launch_bounds__(256, 2) void attn_kernel(const unsigned short* __restrict__ Qb,
                                                      const unsigned short* __restrict__ Kb,
                                                      const unsigned short* __restrict__ Vtb,
                                                      const unsigned short* __restrict__ EI,
                                                      const float* __restrict__ beta,
                                                      unsigned short* __restrict__ hb) {
    // per buffer (16KB): K tile 8KB | V tile 8KB
    __shared__ __align__(16) char smem[2][16384];
    const int tid = threadIdx.x;
    const int w = tid >> 6, l = tid & 63;
    const int g = l >> 4, c = l & 15;

    // XCD-grouping swizzle: 8 head-blocks sharing one (b,q64) EI slice -> same XCD.
    const int p = blockIdx.x;                 // 0..511
    const int s = (p & 7) + 8 * (p >> 6);     // (b, qb) index 0..63
    const int h = (p >> 3) & 7;
    const int b = s >> 4, qb = s & 15;
    const int bh = b * 8 + h;
    const int q0 = qb * 64 + w * 16;
    const int qt = qb * 4 + w;

    const unsigned short* Qrow = Qb + ((size_t)bh * L_ + q0 + c) * D_;
    const bf16x8 qf0 = *(const bf16x8*)(Qrow + g * 8);
    const bf16x8 qf1 = *(const bf16x8*)(Qrow + 32 + g * 8);

    const unsigned short* Kbase = Kb + (size_t)bh * L_ * D_;   // row stride 64
    const unsigned short* Vbase = Vtb + (size_t)bh * D_ * L_;  // row stride 1024
    const unsigned short* Ebase = EI + ((size_t)(b * 64 + qt) * 64) * 512;

    f32x4 O[3][4];
#pragma unroll
    for (int j = 0; j < 3; ++j)
#pragma unroll
        for (int dc = 0; dc < 4; ++dc) O[j][dc] = (f32x4){0.f, 0.f, 0.f, 0.f};
    float lsum0 = 0.f, lsum1 = 0.f, lsum2 = 0.f;

    const int srow = l >> 3, sm = l & 7;       // staging row-within-8, chunk
    const int key = (c & 7) << 4;              // read-side swizzle key

    auto stage = [&](int t, char* base) {
#pragma unroll
        for (int n = 0; n < 2; ++n) {
            int i = 2 * w + n;
            int row = i * 8 + srow;
            int sw = (sm ^ (row & 7)) * 8;     // pre-swizzled global source
            gload16(Kbase + (size_t)(t * 64 + row) * D_ + sw, base + i * 1024);
            gload16(Vbase + (size_t)row * L_ + t * 64 + sw, base + 8192 + i * 1024);
        }
    };
    auto eload = [&](EReg& X, int t) {
#pragma unroll
        for (int ks = 0; ks < 4; ++ks)
            X.e[ks] = *(const bf16x8*)(Ebase + (size_t)(t * 4 + ks) * 512 + l * 8);
    };

    auto compute = [&](const char* base, const EReg& E) {
        const char* Kl = base;
        const char* Vl = base + 8192;
        unsigned rr[4][3][2];
#pragma unroll
        for (int st = 0; st < 4; ++st) {
            const char* kr = Kl + (st * 16 + c) * 128;
            bf16x8 ka = *(const bf16x8*)(kr + ((g * 16) ^ key));
            bf16x8 kb = *(const bf16x8*)(kr + ((64 + g * 16) ^ key));
            f32x4 sacc = (f32x4){0.f, 0.f, 0.f, 0.f};
            sacc = __builtin_amdgcn_mfma_f32_16x16x32_bf16(ka, qf0, sacc, 0, 0, 0);
            sacc = __builtin_amdgcn_mfma_f32_16x16x32_bf16(kb, qf1, sacc, 0, 0, 0);
            float pv[3][4];
#pragma unroll
            for (int i = 0; i < 4; ++i) {
                float p0 = __expf(sacc[i] * 0.125f);
                float p1 = p0 * bf2f((unsigned short)E.e[st][i]);
                float p2 = p0 * bf2f((unsigned short)E.e[st][4 + i]);
                lsum0 += p0; lsum1 += p1; lsum2 += p2;
                pv[0][i] = p0; pv[1][i] = p1; pv[2][i] = p2;
            }
#pragma unroll
            for (int j = 0; j < 3; ++j) {
                rr[st][j][0] = __builtin_amdgcn_perm(__float_as_uint(pv[j][1]), __float_as_uint(pv[j][0]), 0x07060302u);
                rr[st][j][1] = __builtin_amdgcn_perm(__float_as_uint(pv[j][3]), __float_as_uint(pv[j][2]), 0x07060302u);
            }
        }
#pragma unroll
        for (int kk = 0; kk < 2; ++kk) {
            bf16x8 af[3];
#pragma unroll
            for (int j = 0; j < 3; ++j) {
                union { unsigned u[4]; bf16x8 v; } t_;
                t_.u[0] = rr[2 * kk][j][0];     t_.u[1] = rr[2 * kk][j][1];
                t_.u[2] = rr[2 * kk + 1][j][0]; t_.u[3] = rr[2 * kk + 1][j][1];
                af[j] = t_.v;
            }
#pragma unroll
            for (int dc = 0; dc < 4; ++dc) {
                const char* vr = Vl + (dc * 16 + c) * 128;
                u32x2 vlo = *(const u32x2*)(vr + ((kk * 64 + g * 8) ^ key));
                u32x2 vhi = *(const u32x2*)(vr + ((kk * 64 + 32 + g * 8) ^ key));
                union { unsigned u[4]; bf16x8 v; } bv;
                bv.u[0] = vlo[0]; bv.u[1] = vlo[1]; bv.u[2] = vhi[0]; bv.u[3] = vhi[1];
#pragma unroll
                for (int j = 0; j < 3; ++j)
                    O[j][dc] = __builtin_amdgcn_mfma_f32_16x16x32_bf16(af[j], bv.v, O[j][dc], 0, 0, 0);
            }
        }
    };

    EReg E0, E1;
    stage(0, smem[0]);
    eload(E0, 0);
    __syncthreads();
#pragma unroll 1
    for (int t = 0; t < 16; t += 2) {
        stage(t + 1, smem[1]);
        eload(E1, t + 1);
        compute(smem[0], E0);
        __syncthreads();
        if (t + 2 < 16) { stage(t + 2, smem[0]); eload(E0, t + 2); }
        compute(smem[1], E1);
        __syncthreads();
    }

    // reduce lsum over g-groups (k partitioned across g)
    lsum0 += __shfl_xor(lsum0, 16); lsum0 += __shfl_xor(lsum0, 32);
    lsum1 += __shfl_xor(lsum1, 16); lsum1 += __shfl_xor(lsum1, 32);
    lsum2 += __shfl_xor(lsum2, 16); lsum2 += __shfl_xor(lsum2, 32);

    float b0 = beta[0], b1 = beta[1], b2 = beta[2];
    float bm = fmaxf(b0, fmaxf(b1, b2));
    float e0 = __expf(b0 - bm), e1 = __expf(b1 - bm), e2 = __expf(b2 - bm);
    float inv = 1.0f / (e0 + e1 + e2);
    float i0 = e0 * inv / lsum0, i1 = e1 * inv / lsum1, i2 = e2 * inv / lsum2;

    float iq0[4], iq1[4], iq2[4];
#pragma unroll
    for (int ii = 0; ii < 4; ++ii) {
        iq0[ii] = __shfl(i0, g * 4 + ii);
        iq1[ii] = __shfl(i1, g * 4 + ii);
        iq2[ii] = __shfl(i2, g * 4 + ii);
    }
    const int hcol = (bh & 7) * 64;
#pragma unroll
    for (int dc = 0; dc < 4; ++dc) {
#pragma unroll
        for (int ii = 0; ii < 4; ++ii) {
            float hv = iq0[ii] * O[0][dc][ii] + iq1[ii] * O[1][dc][ii] + iq2[ii] * O[2][dc][ii];
            int qrow = q0 + g * 4 + ii;
            hb[((size_t)(b << 10) + qrow) * C_ + hcol + dc * 16 + c] = f2bf(hv);
        }
    }
}

extern "C" void kernel_launch(void* const* d_in, const int* in_sizes, int n_in,
                              void* d_out, int out_size, void* d_ws, size_t ws_size,
                              hipStream_t stream) {
    const float* x          = (const float*)d_in[0];
    const float* adj        = (const float*)d_in[1];
    const float* wqkv       = (const float*)d_in[2];
    const float* wproj      = (const float*)d_in[3];
    const float* bias_scale = (const float*)d_in[4];
    const float* beta       = (const float*)d_in[5];
    float* out = (float*)d_out;

    char* ws = (char*)d_ws;
    size_t off = 0;
    auto alloc = [&](size_t bytes) {
        void* p = ws + off;
        off += (bytes + 255) & ~(size_t)255;
        return p;
    };
    unsigned short* xb     = (unsigned short*)alloc((size_t)M_ * C_ * 2);
    unsigned short* wqkvb  = (unsigned short*)alloc((size_t)3 * C_ * C_ * 2);
    unsigned short* wprojb = (unsigned short*)alloc((size_t)C_ * C_ * 2);
    unsigned short* Qb     = (unsigned short*)alloc((size_t)BH_ * L_ * D_ * 2);
    unsigned short* Kb     = (unsigned short*)alloc((size_t)BH_ * L_ * D_ * 2);
    unsigned short* Vtb    = (unsigned short*)alloc((size_t)BH_ * D_ * L_ * 2);
    unsigned short* EI     = (unsigned short*)alloc((size_t)B_ * L_ * L_ * 4);  // ef+eb: B*L*L*2 bf16
    unsigned short* hb     = (unsigned short*)alloc((size_t)M_ * C_ * 2);

    cvt_all<<<(NX4 + NWQ4 + NWP4 + 255) / 256, 256, 0, stream>>>(x, wqkv, wproj, xb, wqkvb, wprojb);
    prep_e<<<dim3(16, 16, B_), 256, 0, stream>>>(adj, bias_scale, EI);
    gemm_bf16<64, 128, 512, 0, 0><<<dim3(1536 / 128, M_ / 64), 256, 0, stream>>>(xb, wqkvb, nullptr, Qb, Kb, Vtb);
    attn_kernel<<<dim3(512), 256, 0, stream>>>(Qb, Kb, Vtb, EI, beta, hb);
    gemm_bf16<64, 64, 512, 1, 512><<<dim3(512 / 64, M_ / 64), 256, 0, stream>>>(hb, wprojb, out, nullptr, nullptr, nullptr);
}